// Round 12
// baseline (537.051 us; speedup 1.0000x reference)
//
#include <hip/hip_runtime.h>
#include <math.h>

#define NN 25000
#define EE 400000
#define FF 128
#define DD 16
#define HH 64
#define HIDC 128
#define OUTC 32
#define GG 64
#define NODEBLK 782     // ceil(25000/32)  (P precompute blocks, fused into k_hist)
#define SCATBLK 1563    // ceil(400000/256)
#define NTILES 1563     // ceil(25000/16)  (MFMA node tiles)
#define ZBLK 128        // zero-fill blocks fused into k_hist

// k_edge grid: 6250 blocks = 25000 waves, ONE 16-edge group per wave.
// R9 lesson: in-flight dst-window L2 locality >> prologue amortization.
#define EDGEBLK 6250
#define HS_STRIDE 68    // s_hs row stride: 2-way banks (free), LDS 18944B
#define RECB 64         // edge record: {int dst, int src, 8B pad, 16 bf16 attr, 16B pad}

// ---- precomputed weight-fragment buffer layout (units: shorts, per layer) ----
#define WQ_NW1 0            // 24 split frags (nc*6+kc)          -> 24576
#define WQ_NW2 24576        // 16 split frags (nc*2+kc)          -> 16384
#define WQ_WN  40960        // 32 split frags (nc*4+kc), L0 only -> 32768
#define WQ_EW  73728        //  8 bf16 frags (kc*4+nc)           -> 4096
#define WQ_W3  77824        //  4 bf16 frags (nc)                -> 2048
#define WQ_LAYER 81920

typedef __attribute__((ext_vector_type(8))) short short8;
typedef __attribute__((ext_vector_type(8))) unsigned short u16x8;
typedef __attribute__((ext_vector_type(4))) float f32x4;

union S8 { short8 v; unsigned short u[8]; };
union U8 { u16x8 v; unsigned short u[8]; };

__device__ __forceinline__ float silu_f(float v) {
    return v / (1.f + __expf(-v));
}

__device__ __forceinline__ unsigned short f2bf_rne(float f) {
  unsigned u = __float_as_uint(f);
  unsigned r = u + 0x7fffu + ((u >> 16) & 1u);
  return (unsigned short)(r >> 16);
}
__device__ __forceinline__ float bfbits2f(unsigned short b) {
  return __uint_as_float(((unsigned)b) << 16);
}

__device__ __forceinline__ void split8(const float* hv, S8& hi, S8& lo) {
#pragma unroll
  for (int j = 0; j < 8; ++j) {
    const unsigned short hb = (unsigned short)(__float_as_uint(hv[j]) >> 16);
    hi.u[j] = hb;
    lo.u[j] = f2bf_rne(hv[j] - bfbits2f(hb));
  }
}

// 3-term split product: err ~2^-16 (near-fp32)
__device__ __forceinline__ f32x4 mfma3(const S8& ah, const S8& al,
                                       const S8& bh, const S8& bl, f32x4 c) {
  c = __builtin_amdgcn_mfma_f32_16x16x32_bf16(ah.v, bh.v, c, 0, 0, 0);
  c = __builtin_amdgcn_mfma_f32_16x16x32_bf16(al.v, bh.v, c, 0, 0, 0);
  c = __builtin_amdgcn_mfma_f32_16x16x32_bf16(ah.v, bl.v, c, 0, 0, 0);
  return c;
}

// ---- weight-prep helpers: identical numerics to in-kernel loadBsplit ----
__device__ __forceinline__ void prepSplit(unsigned short* dst, const float* __restrict__ W,
                                          int ldw, int k0, int n0, int q, int m, int lane) {
  S8 hi, lo;
#pragma unroll
  for (int j = 0; j < 8; ++j) {
    const float wv = W[(size_t)(k0 + q * 8 + j) * ldw + n0 + m];
    const unsigned short hb = (unsigned short)(__float_as_uint(wv) >> 16);
    hi.u[j] = hb;
    lo.u[j] = f2bf_rne(wv - bfbits2f(hb));
  }
  *(short8*)(dst + lane * 8) = hi.v;
  *(short8*)(dst + 512 + lane * 8) = lo.v;
}

__device__ __forceinline__ void prepB16(unsigned short* dst, const float* __restrict__ W,
                                        int ldw, int k0, int n0, int q, int m, int lane,
                                        bool zero) {
  S8 b;
#pragma unroll
  for (int j = 0; j < 8; ++j)
    b.u[j] = zero ? (unsigned short)0
                  : f2bf_rne(W[(size_t)(k0 + q * 8 + j) * ldw + n0 + m]);
  *(short8*)(dst + lane * 8) = b.v;
}

// ------ Dispatch 1: P-precompute + histogram + weight prep + zero-fill (fused) ------
// Precompute blocks (VALU-dense) co-schedule into the histogram's atomic-latency
// shadow; no dependency on hist/scan (needs only X, mlp_w[0]).
__global__ __launch_bounds__(256) void k_hist(
    const int* __restrict__ ei, int* __restrict__ cnt,
    const float* __restrict__ nw1_0, const float* __restrict__ nw2_0,
    const float* __restrict__ mlp0, const float* __restrict__ ew0,
    const float* __restrict__ nw1_1, const float* __restrict__ nw2_1,
    const float* __restrict__ mlp1, const float* __restrict__ ew1,
    unsigned short* __restrict__ wq,
    f32x4* __restrict__ zbase, int zn16,
    const float* __restrict__ X,
    float* __restrict__ P1, unsigned short* __restrict__ P2h) {
  __shared__ __align__(16) float xT[4][128 * 12];
  if (blockIdx.x < NODEBLK) {
    // ---- layer-0 P precompute (VALU matmul; independent of sort chain) ----
    const int w = threadIdx.x >> 6, lane = threadIdx.x & 63;
    float* xt = xT[w];
    const int nb = (blockIdx.x * 4 + w) * 8;
#pragma unroll
    for (int e = 0; e < 8; ++e) {
      const int n = nb + e;
      const bool v = n < NN;
      xt[lane * 12 + e]        = v ? X[n * FF + lane] : 0.f;
      xt[(lane + 64) * 12 + e] = v ? X[n * FF + 64 + lane] : 0.f;
    }
    __syncthreads();
    float a1[8], a2[8];
#pragma unroll
    for (int e = 0; e < 8; ++e) { a1[e] = 0.f; a2[e] = 0.f; }
#pragma unroll 4
    for (int k = 0; k < 128; ++k) {
      const float wa = mlp0[k * 64 + lane];
      const float wb = mlp0[(128 + k) * 64 + lane];
      float xk[8];
      *(f32x4*)&xk[0] = *(const f32x4*)&xt[k * 12];
      *(f32x4*)&xk[4] = *(const f32x4*)&xt[k * 12 + 4];
#pragma unroll
      for (int e = 0; e < 8; ++e) {
        a1[e] = fmaf(xk[e], wa, a1[e]);
        a2[e] = fmaf(xk[e], wb, a2[e]);
      }
    }
#pragma unroll
    for (int e = 0; e < 8; ++e) {
      const int n = nb + e;
      if (n < NN) {
        P1[n * 64 + lane]  = a1[e];
        P2h[n * 64 + lane] = f2bf_rne(a2[e]);
      }
    }
    return;
  }
  const int bb = blockIdx.x - NODEBLK;
  if (bb < SCATBLK) {
    const int t = bb * 256 + threadIdx.x;
    if (t < EE) atomicAdd(&cnt[ei[EE + t]], 1);
    return;
  }
  if (bb >= SCATBLK + 2) {
    // zero-fill blocks: e_agg/cu/g_sum/g_cnt (consumed only by later kernels)
    const int z = bb - SCATBLK - 2;
    const f32x4 zero = {0.f, 0.f, 0.f, 0.f};
    for (int i = z * 256 + threadIdx.x; i < zn16; i += ZBLK * 256)
      zbase[i] = zero;
    return;
  }
  // 2 blocks: per-layer weight fragment precompute
  const int l = bb - SCATBLK;
  const float* nw1 = l ? nw1_1 : nw1_0;
  const float* nw2 = l ? nw2_1 : nw2_0;
  const float* mlw = l ? mlp1 : mlp0;
  const float* ew  = l ? ew1 : ew0;
  unsigned short* base = wq + (size_t)l * WQ_LAYER;
  const int tid = threadIdx.x, w = tid >> 6, lane = tid & 63;
  const int q = lane >> 4, m = lane & 15;
  for (int f = w; f < 24; f += 4)       // nw1: (192,64), frag = nc*6+kc
    prepSplit(base + WQ_NW1 + f * 1024, nw1, 64, (f % 6) * 32, (f / 6) * 16, q, m, lane);
  for (int f = w; f < 16; f += 4)       // nw2: (64,128), frag = nc*2+kc
    prepSplit(base + WQ_NW2 + f * 1024, nw2, 128, (f & 1) * 32, (f >> 1) * 16, q, m, lane);
  if (l == 0) {                          // Wn = mlp_w[1] rows 0..255, frag = nc*4+kc
    for (int f = w; f < 32; f += 4) {
      const int nc = f >> 2, kc = f & 3;
      prepSplit(base + WQ_WN + f * 1024, mlp1 + (size_t)(nc < 4 ? 0 : 128 * 64), 64,
                kc * 32, (nc & 3) * 16, q, m, lane);
    }
  }
  for (int f = w; f < 8; f += 4)        // edge_w bf16, frag = kc*4+nc
    prepB16(base + WQ_EW + f * 512, ew, 64, (f >> 2) * 32, (f & 3) * 16, q, m, lane, false);
  for (int f = w; f < 4; f += 4)        // mlp_w rows 256..271 bf16, frag = nc
    prepB16(base + WQ_W3 + f * 512, mlw + 256 * 64, 64, 0, f * 16, q, m, lane, lane >= 32);
}

// ---------------- Sort step 2: exclusive scan ----------------
__global__ __launch_bounds__(1024) void k_scan(
    const int* __restrict__ cnt, int* __restrict__ row_ptr, int* __restrict__ next) {
  __shared__ int s[1024];
  const int t = threadIdx.x;
  const int base = t * 25;
  int loc[25];
  int sum = 0;
#pragma unroll
  for (int i = 0; i < 25; ++i) {
    const int n = base + i;
    loc[i] = (n < NN) ? cnt[n] : 0;
    sum += loc[i];
  }
  s[t] = sum;
  __syncthreads();
  for (int off = 1; off < 1024; off <<= 1) {
    const int v = (t >= off) ? s[t - off] : 0;
    __syncthreads();
    s[t] += v;
    __syncthreads();
  }
  int run = s[t] - sum;
#pragma unroll
  for (int i = 0; i < 25; ++i) {
    const int n = base + i;
    if (n < NN) {
      row_ptr[n] = run;
      next[n] = run;
      run += loc[i];
    }
  }
  if (t == 0) row_ptr[NN] = EE;
}

// ------- Scatter only: 64B AoS record {dst,src,attr-bf16} ----
// eattr read SEQUENTIAL; full-line record write (no read-for-ownership).
__global__ __launch_bounds__(256) void k_sp(
    const int* __restrict__ ei, int* __restrict__ next,
    char* __restrict__ rec, const float* __restrict__ eattr) {
  const int t = blockIdx.x * 256 + threadIdx.x;
  if (t < EE) {
    const int d = ei[EE + t];
    const int s = ei[t];
    const int slot = atomicAdd(&next[d], 1);
    const float* ep = &eattr[(size_t)t * DD];
    S8 a0, a1;
#pragma unroll
    for (int j = 0; j < 8; ++j) {
      a0.u[j] = f2bf_rne(ep[j]);
      a1.u[j] = f2bf_rne(ep[8 + j]);
    }
    char* rp = rec + (size_t)slot * RECB;
    int hdr[4] = {d, s, 0, 0};
    const f32x4 z4 = {0.f, 0.f, 0.f, 0.f};
    *(f32x4*)rp = *(const f32x4*)hdr;          // 16B: dst,src,pad
    *(short8*)(rp + 16) = a0.v;                // 16B attr lo
    *(short8*)(rp + 32) = a1.v;                // 16B attr hi
    *(f32x4*)(rp + 48) = z4;                   // pad -> full 64B line written
  }
}

// ---------------- K2: per-edge MLP via MFMA, dst-sorted -----------
// ONE 16-edge group per wave (25000 waves): narrow in-flight dst window keeps
// P1 reads + e_agg atomics L2-local. Register fast path for <=2 runs.
// launch_bounds (256,8): kernel fits 60 VGPR <= 64 budget at 8 waves/EU ->
// no spill expected (R2's spill was a fatter kernel); enables 8 blocks/CU.
template <bool COORD>
__global__ __launch_bounds__(256, 8) void k_edge(
    const float* __restrict__ P1, const unsigned short* __restrict__ P2h,
    const float* __restrict__ pos, const char* __restrict__ rec,
    const unsigned short* __restrict__ wq, const float* __restrict__ mlp_w,
    const float* __restrict__ edge_b,
    const float* __restrict__ coord_w, const float* __restrict__ coord_b,
    float* __restrict__ e_agg, float* __restrict__ cu) {
  __shared__ __align__(16) float s_hs[4][16 * HS_STRIDE];
  __shared__ float s_diff[4][48];
  __shared__ float s_rad[4][16];
  __shared__ float s_red[4][16];
  const int tid = threadIdx.x, w = tid >> 6, lane = tid & 63;
  const int q = lane >> 4, m = lane & 15;

  const int g = blockIdx.x * 4 + w;                     // group id, 0..24999
  const int eb = g * 16;
  const char* rp = rec + (size_t)(eb + m) * RECB;
  const int dm = ((const int*)rp)[0];
  const int sm = ((const int*)rp)[1];

  S8 wB[2][4];
#pragma unroll
  for (int kc = 0; kc < 2; ++kc)
#pragma unroll
    for (int nc = 0; nc < 4; ++nc)
      wB[kc][nc].v = *(const short8*)(wq + WQ_EW + (kc * 4 + nc) * 512 + lane * 8);
  S8 w3B[4];
#pragma unroll
  for (int nc = 0; nc < 4; ++nc)
    w3B[nc].v = *(const short8*)(wq + WQ_W3 + nc * 512 + lane * 8);
  float w4r[4], cwr[4], ebr[4];
#pragma unroll
  for (int nc = 0; nc < 4; ++nc) {
    w4r[nc] = mlp_w[272 * 64 + nc * 16 + m];
    ebr[nc] = edge_b[nc * 16 + m];
    cwr[nc] = COORD ? coord_w[nc * 16 + m] : 0.f;
  }
  const float cb = COORD ? coord_b[0] : 0.f;

  const int pe = (lane < 48) ? (lane / 3) : 0;
  const int pc = lane - (lane / 3) * 3;

  f32x4 p1a[2], p1b[2];
  U8 p2r[2];
#pragma unroll
  for (int kc = 0; kc < 2; ++kc) {
    const float* pp1 = P1 + (size_t)dm * 64 + kc * 32 + q * 8;
    p1a[kc] = *(const f32x4*)pp1;
    p1b[kc] = *(const f32x4*)(pp1 + 4);
    p2r[kc].v = *(const u16x8*)(P2h + (size_t)sm * 64 + kc * 32 + q * 8);
  }
  if (lane < 48) {
    const int de = __shfl(dm, pe, 64), se = __shfl(sm, pe, 64);
    s_diff[w][lane] = pos[de * 3 + pc] - pos[se * 3 + pc];
  }
  S8 eaA;
#pragma unroll
  for (int j = 0; j < 8; ++j) eaA.u[j] = 0;
  if (lane < 32) {
    eaA.v = *(const short8*)(rp + 16 + q * 16);
  }
  if (lane < 16) {
    const float d0 = s_diff[w][lane * 3 + 0];
    const float d1 = s_diff[w][lane * 3 + 1];
    const float d2 = s_diff[w][lane * 3 + 2];
    s_rad[w][lane] = fmaf(d0, d0, fmaf(d1, d1, d2 * d2));
  }
  float radr[4];
#pragma unroll
  for (int r = 0; r < 4; ++r) radr[r] = s_rad[w][q * 4 + r];
  f32x4 c3[4];
#pragma unroll
  for (int nc = 0; nc < 4; ++nc) {
    f32x4 z = {0.f, 0.f, 0.f, 0.f};
    c3[nc] = __builtin_amdgcn_mfma_f32_16x16x32_bf16(eaA.v, w3B[nc].v, z, 0, 0, 0);
  }
#pragma unroll
  for (int nc = 0; nc < 4; ++nc)
#pragma unroll
    for (int r = 0; r < 4; ++r)
      s_hs[w][(q * 4 + r) * HS_STRIDE + nc * 16 + m] = fmaf(radr[r], w4r[nc], c3[nc][r]);
  S8 ahi[2], alo[2];
#pragma unroll
  for (int kc = 0; kc < 2; ++kc) {
    const float* hp = &s_hs[w][m * HS_STRIDE + kc * 32 + q * 8];
    f32x4 h0 = *(const f32x4*)hp;
    f32x4 h1 = *(const f32x4*)(hp + 4);
    h0 = h0 + p1a[kc];
    h1 = h1 + p1b[kc];
    float hv[8];
    *(f32x4*)&hv[0] = h0;
    *(f32x4*)&hv[4] = h1;
#pragma unroll
    for (int j = 0; j < 8; ++j) {
      const float h = silu_f(hv[j] + bfbits2f(p2r[kc].u[j]));
      const unsigned short hb = (unsigned short)(__float_as_uint(h) >> 16);
      ahi[kc].u[j] = hb;
      alo[kc].u[j] = f2bf_rne(h - bfbits2f(hb));
    }
  }
  f32x4 o[4];
#pragma unroll
  for (int nc = 0; nc < 4; ++nc) {
    f32x4 bi = {ebr[nc], ebr[nc], ebr[nc], ebr[nc]};
    o[nc] = bi;
  }
#pragma unroll
  for (int kc = 0; kc < 2; ++kc)
#pragma unroll
    for (int nc = 0; nc < 4; ++nc) {
      o[nc] = __builtin_amdgcn_mfma_f32_16x16x32_bf16(ahi[kc].v, wB[kc][nc].v, o[nc], 0, 0, 0);
      o[nc] = __builtin_amdgcn_mfma_f32_16x16x32_bf16(alo[kc].v, wB[kc][nc].v, o[nc], 0, 0, 0);
    }
#pragma unroll
  for (int nc = 0; nc < 4; ++nc)
#pragma unroll
    for (int r = 0; r < 4; ++r) o[nc][r] = silu_f(o[nc][r]);
  if (COORD) {
#pragma unroll
    for (int r = 0; r < 4; ++r) {
      float v = o[0][r] * cwr[0] + o[1][r] * cwr[1] + o[2][r] * cwr[2] + o[3][r] * cwr[3];
      v += __shfl_xor(v, 1, 64);
      v += __shfl_xor(v, 2, 64);
      v += __shfl_xor(v, 4, 64);
      v += __shfl_xor(v, 8, 64);
      if (m == 0) s_red[w][q * 4 + r] = v;
    }
  }

  // ---- e_agg reduction: run detection (dst sorted => monotone within group) ----
  const int d0  = __shfl(dm, 0, 64);
  const int d15 = __shfl(dm, 15, 64);
  const unsigned m1 = (unsigned)__ballot(lane < 16 && dm != d0) & 0xFFFFu;
  int b = 16;
  bool fast = true;
  if (m1 != 0) {
    b = __builtin_ctz(m1);
    const unsigned m2 = (unsigned)__ballot(lane < 16 && dm != d15) & 0xFFFFu;
    fast = (m2 == ((1u << b) - 1u));   // exactly two runs
  }
  if (fast) {
    float s0[4], s1[4];
#pragma unroll
    for (int nc = 0; nc < 4; ++nc) {
      s0[nc] = 0.f; s1[nc] = 0.f;
#pragma unroll
      for (int r = 0; r < 4; ++r) {
        const bool in0 = (q * 4 + r) < b;
        s0[nc] += in0 ? o[nc][r] : 0.f;
        s1[nc] += in0 ? 0.f : o[nc][r];
      }
    }
#pragma unroll
    for (int nc = 0; nc < 4; ++nc) {
      s0[nc] += __shfl_xor(s0[nc], 16, 64);
      s0[nc] += __shfl_xor(s0[nc], 32, 64);
    }
    const float v0 = (q == 0) ? s0[0] : (q == 1) ? s0[1] : (q == 2) ? s0[2] : s0[3];
    atomicAdd(&e_agg[(size_t)d0 * 64 + lane], v0);
    if (b < 16) {
#pragma unroll
      for (int nc = 0; nc < 4; ++nc) {
        s1[nc] += __shfl_xor(s1[nc], 16, 64);
        s1[nc] += __shfl_xor(s1[nc], 32, 64);
      }
      const float v1 = (q == 0) ? s1[0] : (q == 1) ? s1[1] : (q == 2) ? s1[2] : s1[3];
      atomicAdd(&e_agg[(size_t)d15 * 64 + lane], v1);
    }
  } else {
    // fallback: LDS transpose + serial run-compress (>=3 runs, rare)
#pragma unroll
    for (int nc = 0; nc < 4; ++nc)
#pragma unroll
      for (int r = 0; r < 4; ++r)
        s_hs[w][(q * 4 + r) * HS_STRIDE + nc * 16 + m] = o[nc][r];
    int cur_dst = -1;
    float accum = 0.f;
    for (int e = 0; e < 16; ++e) {
      const int dv = __shfl(dm, e, 64);
      const float v = s_hs[w][e * HS_STRIDE + lane];
      if (dv == cur_dst) {
        accum += v;
      } else {
        if (cur_dst >= 0) atomicAdd(&e_agg[(size_t)cur_dst * 64 + lane], accum);
        cur_dst = dv;
        accum = v;
      }
    }
    if (cur_dst >= 0) atomicAdd(&e_agg[(size_t)cur_dst * 64 + lane], accum);
  }

  if (COORD) {
    if (lane < 48) {
      const float s = silu_f(s_red[w][pe] + cb);
      atomicAdd(&cu[(size_t)__shfl(dm, pe, 64) * 3 + pc], s_diff[w][lane] * s);
    }
  }
}

// ------- K3: node MLP via MFMA (3-term split, near-fp32). COOPERATIVE:
// 4 waves share one 16-node tile (wave w owns h1 chunk nc=w, h2/P chunks w,w+4).
template <bool L0>
__global__ __launch_bounds__(256) void k_node(
    const float* __restrict__ x_in, float* __restrict__ e_agg,
    const unsigned short* __restrict__ wq,
    const float* __restrict__ nb1, const float* __restrict__ nb2,
    const float* __restrict__ pos_in, const float* __restrict__ cu,
    const int* __restrict__ row_ptr,
    float* __restrict__ x_out, float* __restrict__ pos_out,
    float* __restrict__ P1, unsigned short* __restrict__ P2h,
    const int* __restrict__ batch,
    float* __restrict__ g_sum, float* __restrict__ g_cnt) {
  __shared__ __align__(16) float sb[16 * 132];   // stride 132: 2-way banks (free)
  const int tid = threadIdx.x, w = tid >> 6, lane = tid & 63;
  const int q = lane >> 4, m = lane & 15;
  const int n0 = blockIdx.x * 16;
  const int nm = n0 + m;
  const bool vm = nm < NN;

  // ---- stage 1: A = [x | e_agg] (K=192), split hi/lo (all 4 waves; L1-shared)
  S8 axh[6], axl[6];
#pragma unroll
  for (int kc = 0; kc < 6; ++kc) {
    float hv[8] = {0.f, 0.f, 0.f, 0.f, 0.f, 0.f, 0.f, 0.f};
    if (vm) {
      const float* src = (kc < 4) ? (x_in + (size_t)nm * HIDC + kc * 32 + q * 8)
                                  : (e_agg + (size_t)nm * 64 + (kc - 4) * 32 + q * 8);
      *(f32x4*)&hv[0] = *(const f32x4*)src;
      *(f32x4*)&hv[4] = *(const f32x4*)(src + 4);
    }
    split8(hv, axh[kc], axl[kc]);
  }
  // ---- h1 chunk nc=w: silu(A @ nw1 + nb1) ----
  {
    const float b = nb1[w * 16 + m];
    f32x4 acc = {b, b, b, b};
#pragma unroll
    for (int kc = 0; kc < 6; ++kc) {
      S8 bh, bl;
      const unsigned short* fb = wq + WQ_NW1 + (w * 6 + kc) * 1024 + lane * 8;
      bh.v = *(const short8*)fb;
      bl.v = *(const short8*)(fb + 512);
      acc = mfma3(axh[kc], axl[kc], bh, bl, acc);
    }
#pragma unroll
    for (int r = 0; r < 4; ++r)
      sb[(q * 4 + r) * 132 + w * 16 + m] = silu_f(acc[r]);
  }
  __syncthreads();
  if (L0 && vm && w == 3) {   // pre-zero e_agg for layer 1 (after all waves read it)
    const f32x4 z = {0.f, 0.f, 0.f, 0.f};
    float* ez = e_agg + (size_t)nm * 64 + q * 8;
    *(f32x4*)ez = z; *(f32x4*)(ez + 4) = z;
    *(f32x4*)(ez + 32) = z; *(f32x4*)(ez + 36) = z;
  }
  // ---- read full h1 as A-fragments, split ----
  S8 ah[2], al[2];
#pragma unroll
  for (int kc = 0; kc < 2; ++kc) {
    float hv[8];
    const float* hp = &sb[m * 132 + kc * 32 + q * 8];
    *(f32x4*)&hv[0] = *(const f32x4*)hp;
    *(f32x4*)&hv[4] = *(const f32x4*)(hp + 4);
    split8(hv, ah[kc], al[kc]);
  }
  // ---- h2 chunks nc = w, w+4 ----
  f32x4 hh[2];
#pragma unroll
  for (int i = 0; i < 2; ++i) {
    const int nc = w + i * 4;
    const float b = nb2[nc * 16 + m];
    f32x4 acc = {b, b, b, b};
#pragma unroll
    for (int kc = 0; kc < 2; ++kc) {
      S8 bh, bl;
      const unsigned short* fb = wq + WQ_NW2 + (nc * 2 + kc) * 1024 + lane * 8;
      bh.v = *(const short8*)fb;
      bl.v = *(const short8*)(fb + 512);
      acc = mfma3(ah[kc], al[kc], bh, bl, acc);
    }
    hh[i] = acc;
  }
  if (L0) {
    __syncthreads();   // all h1 reads done before overwriting sb with x1
#pragma unroll
    for (int i = 0; i < 2; ++i) {
      const int nc = w + i * 4;
#pragma unroll
      for (int r = 0; r < 4; ++r) {
        const int n = n0 + q * 4 + r;
        sb[(q * 4 + r) * 132 + nc * 16 + m] = hh[i][r];
        if (n < NN) x_out[(size_t)n * HIDC + nc * 16 + m] = hh[i][r];
      }
    }
    if (w == 0 && lane < 48) {   // pos update (16 nodes x 3 comps)
      const int pe2 = lane / 3, pc2 = lane - pe2 * 3;
      const int n = n0 + pe2;
      if (n < NN) {
        const float dg = fmaxf((float)(row_ptr[n + 1] - row_ptr[n]), 1.f);
        pos_out[n * 3 + pc2] = pos_in[n * 3 + pc2] + cu[n * 3 + pc2] / dg;
      }
    }
    __syncthreads();
    // ---- P = x1 @ Wn (chunks nc=w -> P1 fp32, nc=w+4 -> P2 bf16) ----
    S8 a1h[4], a1l[4];
#pragma unroll
    for (int kc = 0; kc < 4; ++kc) {
      float hv[8];
      const float* hp = &sb[m * 132 + kc * 32 + q * 8];
      *(f32x4*)&hv[0] = *(const f32x4*)hp;
      *(f32x4*)&hv[4] = *(const f32x4*)(hp + 4);
      split8(hv, a1h[kc], a1l[kc]);
    }
#pragma unroll
    for (int i = 0; i < 2; ++i) {
      const int nc = w + i * 4;
      f32x4 acc = {0.f, 0.f, 0.f, 0.f};
#pragma unroll
      for (int kc = 0; kc < 4; ++kc) {
        S8 bh, bl;
        const unsigned short* fb = wq + WQ_WN + (nc * 4 + kc) * 1024 + lane * 8;
        bh.v = *(const short8*)fb;
        bl.v = *(const short8*)(fb + 512);
        acc = mfma3(a1h[kc], a1l[kc], bh, bl, acc);
      }
#pragma unroll
      for (int r = 0; r < 4; ++r) {
        const int n = n0 + q * 4 + r;
        if (n < NN) {
          if (i == 0) P1[(size_t)n * 64 + w * 16 + m] = acc[r];
          else        P2h[(size_t)n * 64 + w * 16 + m] = f2bf_rne(acc[r]);
        }
      }
    }
  } else {
    // ---- fused mean-pool partials (batch sorted; run-compress per lane) ----
    int curb = -1;
    float cnt2 = 0.f;
    float pacc[2];
#pragma unroll
    for (int r = 0; r < 4; ++r) {
      const int n = n0 + q * 4 + r;
      if (n < NN) {
        const int bg = batch[n];
        if (bg != curb) {
          if (curb >= 0) {
#pragma unroll
            for (int i = 0; i < 2; ++i)
              atomicAdd(&g_sum[curb * HIDC + (w + i * 4) * 16 + m], pacc[i]);
            if (w == 0 && m == 0) atomicAdd(&g_cnt[curb], cnt2);
          }
          curb = bg;
          pacc[0] = hh[0][r];
          pacc[1] = hh[1][r];
          cnt2 = 1.f;
        } else {
          pacc[0] += hh[0][r];
          pacc[1] += hh[1][r];
          cnt2 += 1.f;
        }
      }
    }
    if (curb >= 0) {
#pragma unroll
      for (int i = 0; i < 2; ++i)
        atomicAdd(&g_sum[curb * HIDC + (w + i * 4) * 16 + m], pacc[i]);
      if (w == 0 && m == 0) atomicAdd(&g_cnt[curb], cnt2);
    }
  }
}

// ---------------- K5: relu(mean) -> relu(@w1+b1) -> @w2+b2 ----------------
__global__ __launch_bounds__(128) void k_final(
    const float* __restrict__ g_sum, const float* __restrict__ g_cnt,
    const float* __restrict__ w1, const float* __restrict__ b1,
    const float* __restrict__ w2, const float* __restrict__ b2,
    float* __restrict__ out) {
  __shared__ float sg[128];
  __shared__ float sh[128];
  const int g = blockIdx.x, j = threadIdx.x;
  const float c = fmaxf(g_cnt[g], 1.f);
  sg[j] = fmaxf(g_sum[g * HIDC + j] / c, 0.f);
  __syncthreads();
  float a = b1[j];
  for (int k = 0; k < 128; ++k) a += sg[k] * w1[k * 128 + j];
  sh[j] = fmaxf(a, 0.f);
  __syncthreads();
  if (j < OUTC) {
    float o = b2[j];
    for (int k = 0; k < 128; ++k) o += sh[k] * w2[k * OUTC + j];
    out[g * OUTC + j] = o;
  }
}

extern "C" void kernel_launch(void* const* d_in, const int* in_sizes, int n_in,
                              void* d_out, int out_size, void* d_ws, size_t ws_size,
                              hipStream_t stream) {
  const float* x     = (const float*)d_in[0];
  const float* pos   = (const float*)d_in[1];
  const float* eattr = (const float*)d_in[2];
  const int*   ei    = (const int*)d_in[3];
  const int*   batch = (const int*)d_in[4];
  const float* mlp_w[2]   = {(const float*)d_in[5],  (const float*)d_in[14]};
  const float* edge_w[2]  = {(const float*)d_in[6],  (const float*)d_in[15]};
  const float* edge_b[2]  = {(const float*)d_in[7],  (const float*)d_in[16]};
  const float* coord_w[2] = {(const float*)d_in[8],  (const float*)d_in[17]};
  const float* coord_b[2] = {(const float*)d_in[9],  (const float*)d_in[18]};
  const float* nw1[2]     = {(const float*)d_in[10], (const float*)d_in[19]};
  const float* nb1[2]     = {(const float*)d_in[11], (const float*)d_in[20]};
  const float* nw2[2]     = {(const float*)d_in[12], (const float*)d_in[21]};
  const float* nb2[2]     = {(const float*)d_in[13], (const float*)d_in[22]};
  const float* ow1 = (const float*)d_in[23];
  const float* ob1 = (const float*)d_in[24];
  const float* ow2 = (const float*)d_in[25];
  const float* ob2 = (const float*)d_in[26];
  float* out = (float*)d_out;

  char* p = (char*)d_ws;
  auto alloc = [&](size_t bytes) {
    void* r = (void*)p;
    p += (bytes + 255) & ~(size_t)255;
    return r;
  };
  float* P1            = (float*)alloc((size_t)NN * 64 * 4);
  unsigned short* P2h  = (unsigned short*)alloc((size_t)NN * 64 * 2);
  // ---- cnt: zeroed by small memset (must be 0 BEFORE k_hist's histogram) ----
  int* cnt             = (int*)alloc((size_t)NN * 4);
  // ---- zero-region handled by k_hist's fused zero blocks ----
  char* zero_base      = p;
  float* e_agg         = (float*)alloc((size_t)NN * 64 * 4);
  float* cu            = (float*)alloc((size_t)NN * 3 * 4);
  float* g_sum         = (float*)alloc((size_t)GG * HIDC * 4);
  float* g_cnt         = (float*)alloc((size_t)GG * 4);
  const size_t zero_sz = (size_t)(p - zero_base);
  // ---- non-zeroed scratch ----
  int* row_ptr         = (int*)alloc((size_t)(NN + 1) * 4);
  int* nxt             = (int*)alloc((size_t)NN * 4);
  char* rec            = (char*)alloc((size_t)EE * RECB);
  float* x1            = (float*)alloc((size_t)NN * HIDC * 4);
  float* pos1          = (float*)alloc((size_t)NN * 3 * 4);
  unsigned short* wqb  = (unsigned short*)alloc((size_t)2 * WQ_LAYER * 2);

  (void)hipMemsetAsync(cnt, 0, (size_t)NN * 4, stream);

  // ---- dispatch 1: P-precompute + histogram + weight prep + zero-fill ----
  k_hist<<<NODEBLK + SCATBLK + 2 + ZBLK, 256, 0, stream>>>(ei, cnt,
      nw1[0], nw2[0], mlp_w[0], edge_w[0],
      nw1[1], nw2[1], mlp_w[1], edge_w[1], wqb,
      (f32x4*)zero_base, (int)(zero_sz / 16),
      x, P1, P2h);
  k_scan<<<1, 1024, 0, stream>>>(cnt, row_ptr, nxt);
  k_sp<<<SCATBLK, 256, 0, stream>>>(ei, nxt, rec, eattr);

  // ---- layer 0 ----
  k_edge<true><<<EDGEBLK, 256, 0, stream>>>(P1, P2h, pos, rec,
      wqb, mlp_w[0], edge_b[0], coord_w[0], coord_b[0], e_agg, cu);
  k_node<true><<<NTILES, 256, 0, stream>>>(x, e_agg, wqb, nb1[0], nb2[0],
      pos, cu, row_ptr, x1, pos1, P1, P2h, batch, g_sum, g_cnt);

  // ---- layer 1 ----
  k_edge<false><<<EDGEBLK, 256, 0, stream>>>(P1, P2h, pos1, rec,
      wqb + WQ_LAYER, mlp_w[1], edge_b[1], coord_w[1], coord_b[1], e_agg, cu);
  k_node<false><<<NTILES, 256, 0, stream>>>(x1, e_agg, wqb + WQ_LAYER,
      nb1[1], nb2[1], pos1, cu, row_ptr, x1, pos1, P1, P2h,
      batch, g_sum, g_cnt);

  // ---- head ----
  k_final<<<GG, 128, 0, stream>>>(g_sum, g_cnt, ow1, ob1, ow2, ob2, out);
}

// Round 13
// 413.915 us; speedup vs baseline: 1.2975x; 1.2975x over previous
//
#include <hip/hip_runtime.h>
#include <math.h>

#define NN 25000
#define EE 400000
#define FF 128
#define DD 16
#define HH 64
#define HIDC 128
#define OUTC 32
#define GG 64
#define NODEBLK 782     // ceil(25000/32)  (P precompute blocks, fused into k_hist)
#define SCATBLK 1563    // ceil(400000/256)
#define NTILES 1563     // ceil(25000/16)  (MFMA node tiles)
#define ZBLK 128        // zero-fill blocks fused into k_hist

// k_edge grid: 6250 blocks = 25000 waves, ONE 16-edge group per wave.
// R9 lesson: in-flight dst-window L2 locality >> prologue amortization.
// R12 lesson: (256,8) forces the 32-VGPR tier -> 500MB scratch spill. Keep (256,4).
#define EDGEBLK 6250
#define HS_STRIDE 68    // s_hs row stride: 2-way banks (free), LDS 18944B
#define RECB 64         // edge record: {int dst, int src, 8B pad, 16 bf16 attr, 16B pad}

// ---- precomputed weight-fragment buffer layout (units: shorts, per layer) ----
#define WQ_NW1 0            // 24 split frags (nc*6+kc)          -> 24576
#define WQ_NW2 24576        // 16 split frags (nc*2+kc)          -> 16384
#define WQ_WN  40960        // 32 split frags (nc*4+kc), L0 only -> 32768
#define WQ_EW  73728        //  8 bf16 frags (kc*4+nc)           -> 4096
#define WQ_W3  77824        //  4 bf16 frags (nc)                -> 2048
#define WQ_LAYER 81920

typedef __attribute__((ext_vector_type(8))) short short8;
typedef __attribute__((ext_vector_type(8))) unsigned short u16x8;
typedef __attribute__((ext_vector_type(4))) float f32x4;

union S8 { short8 v; unsigned short u[8]; };
union U8 { u16x8 v; unsigned short u[8]; };

__device__ __forceinline__ float silu_f(float v) {
    return v / (1.f + __expf(-v));
}

__device__ __forceinline__ unsigned short f2bf_rne(float f) {
  unsigned u = __float_as_uint(f);
  unsigned r = u + 0x7fffu + ((u >> 16) & 1u);
  return (unsigned short)(r >> 16);
}
__device__ __forceinline__ float bfbits2f(unsigned short b) {
  return __uint_as_float(((unsigned)b) << 16);
}

__device__ __forceinline__ void split8(const float* hv, S8& hi, S8& lo) {
#pragma unroll
  for (int j = 0; j < 8; ++j) {
    const unsigned short hb = (unsigned short)(__float_as_uint(hv[j]) >> 16);
    hi.u[j] = hb;
    lo.u[j] = f2bf_rne(hv[j] - bfbits2f(hb));
  }
}

// 3-term split product: err ~2^-16 (near-fp32)
__device__ __forceinline__ f32x4 mfma3(const S8& ah, const S8& al,
                                       const S8& bh, const S8& bl, f32x4 c) {
  c = __builtin_amdgcn_mfma_f32_16x16x32_bf16(ah.v, bh.v, c, 0, 0, 0);
  c = __builtin_amdgcn_mfma_f32_16x16x32_bf16(al.v, bh.v, c, 0, 0, 0);
  c = __builtin_amdgcn_mfma_f32_16x16x32_bf16(ah.v, bl.v, c, 0, 0, 0);
  return c;
}

// ---- weight-prep helpers: identical numerics to in-kernel loadBsplit ----
__device__ __forceinline__ void prepSplit(unsigned short* dst, const float* __restrict__ W,
                                          int ldw, int k0, int n0, int q, int m, int lane) {
  S8 hi, lo;
#pragma unroll
  for (int j = 0; j < 8; ++j) {
    const float wv = W[(size_t)(k0 + q * 8 + j) * ldw + n0 + m];
    const unsigned short hb = (unsigned short)(__float_as_uint(wv) >> 16);
    hi.u[j] = hb;
    lo.u[j] = f2bf_rne(wv - bfbits2f(hb));
  }
  *(short8*)(dst + lane * 8) = hi.v;
  *(short8*)(dst + 512 + lane * 8) = lo.v;
}

__device__ __forceinline__ void prepB16(unsigned short* dst, const float* __restrict__ W,
                                        int ldw, int k0, int n0, int q, int m, int lane,
                                        bool zero) {
  S8 b;
#pragma unroll
  for (int j = 0; j < 8; ++j)
    b.u[j] = zero ? (unsigned short)0
                  : f2bf_rne(W[(size_t)(k0 + q * 8 + j) * ldw + n0 + m]);
  *(short8*)(dst + lane * 8) = b.v;
}

// ------ Dispatch 1: P-precompute + histogram + weight prep + zero-fill (fused) ------
// Precompute blocks (VALU-dense) co-schedule into the histogram's atomic-latency
// shadow; no dependency on hist/scan (needs only X, mlp_w[0]).
__global__ __launch_bounds__(256) void k_hist(
    const int* __restrict__ ei, int* __restrict__ cnt,
    const float* __restrict__ nw1_0, const float* __restrict__ nw2_0,
    const float* __restrict__ mlp0, const float* __restrict__ ew0,
    const float* __restrict__ nw1_1, const float* __restrict__ nw2_1,
    const float* __restrict__ mlp1, const float* __restrict__ ew1,
    unsigned short* __restrict__ wq,
    f32x4* __restrict__ zbase, int zn16,
    const float* __restrict__ X,
    float* __restrict__ P1, unsigned short* __restrict__ P2h) {
  __shared__ __align__(16) float xT[4][128 * 12];
  if (blockIdx.x < NODEBLK) {
    // ---- layer-0 P precompute (VALU matmul; independent of sort chain) ----
    const int w = threadIdx.x >> 6, lane = threadIdx.x & 63;
    float* xt = xT[w];
    const int nb = (blockIdx.x * 4 + w) * 8;
#pragma unroll
    for (int e = 0; e < 8; ++e) {
      const int n = nb + e;
      const bool v = n < NN;
      xt[lane * 12 + e]        = v ? X[n * FF + lane] : 0.f;
      xt[(lane + 64) * 12 + e] = v ? X[n * FF + 64 + lane] : 0.f;
    }
    __syncthreads();
    float a1[8], a2[8];
#pragma unroll
    for (int e = 0; e < 8; ++e) { a1[e] = 0.f; a2[e] = 0.f; }
#pragma unroll 4
    for (int k = 0; k < 128; ++k) {
      const float wa = mlp0[k * 64 + lane];
      const float wb = mlp0[(128 + k) * 64 + lane];
      float xk[8];
      *(f32x4*)&xk[0] = *(const f32x4*)&xt[k * 12];
      *(f32x4*)&xk[4] = *(const f32x4*)&xt[k * 12 + 4];
#pragma unroll
      for (int e = 0; e < 8; ++e) {
        a1[e] = fmaf(xk[e], wa, a1[e]);
        a2[e] = fmaf(xk[e], wb, a2[e]);
      }
    }
#pragma unroll
    for (int e = 0; e < 8; ++e) {
      const int n = nb + e;
      if (n < NN) {
        P1[n * 64 + lane]  = a1[e];
        P2h[n * 64 + lane] = f2bf_rne(a2[e]);
      }
    }
    return;
  }
  const int bb = blockIdx.x - NODEBLK;
  if (bb < SCATBLK) {
    const int t = bb * 256 + threadIdx.x;
    if (t < EE) atomicAdd(&cnt[ei[EE + t]], 1);
    return;
  }
  if (bb >= SCATBLK + 2) {
    // zero-fill blocks: e_agg/cu/g_sum/g_cnt (consumed only by later kernels)
    const int z = bb - SCATBLK - 2;
    const f32x4 zero = {0.f, 0.f, 0.f, 0.f};
    for (int i = z * 256 + threadIdx.x; i < zn16; i += ZBLK * 256)
      zbase[i] = zero;
    return;
  }
  // 2 blocks: per-layer weight fragment precompute
  const int l = bb - SCATBLK;
  const float* nw1 = l ? nw1_1 : nw1_0;
  const float* nw2 = l ? nw2_1 : nw2_0;
  const float* mlw = l ? mlp1 : mlp0;
  const float* ew  = l ? ew1 : ew0;
  unsigned short* base = wq + (size_t)l * WQ_LAYER;
  const int tid = threadIdx.x, w = tid >> 6, lane = tid & 63;
  const int q = lane >> 4, m = lane & 15;
  for (int f = w; f < 24; f += 4)       // nw1: (192,64), frag = nc*6+kc
    prepSplit(base + WQ_NW1 + f * 1024, nw1, 64, (f % 6) * 32, (f / 6) * 16, q, m, lane);
  for (int f = w; f < 16; f += 4)       // nw2: (64,128), frag = nc*2+kc
    prepSplit(base + WQ_NW2 + f * 1024, nw2, 128, (f & 1) * 32, (f >> 1) * 16, q, m, lane);
  if (l == 0) {                          // Wn = mlp_w[1] rows 0..255, frag = nc*4+kc
    for (int f = w; f < 32; f += 4) {
      const int nc = f >> 2, kc = f & 3;
      prepSplit(base + WQ_WN + f * 1024, mlp1 + (size_t)(nc < 4 ? 0 : 128 * 64), 64,
                kc * 32, (nc & 3) * 16, q, m, lane);
    }
  }
  for (int f = w; f < 8; f += 4)        // edge_w bf16, frag = kc*4+nc
    prepB16(base + WQ_EW + f * 512, ew, 64, (f >> 2) * 32, (f & 3) * 16, q, m, lane, false);
  for (int f = w; f < 4; f += 4)        // mlp_w rows 256..271 bf16, frag = nc
    prepB16(base + WQ_W3 + f * 512, mlw + 256 * 64, 64, 0, f * 16, q, m, lane, lane >= 32);
}

// ---------------- Sort step 2: exclusive scan ----------------
__global__ __launch_bounds__(1024) void k_scan(
    const int* __restrict__ cnt, int* __restrict__ row_ptr, int* __restrict__ next) {
  __shared__ int s[1024];
  const int t = threadIdx.x;
  const int base = t * 25;
  int loc[25];
  int sum = 0;
#pragma unroll
  for (int i = 0; i < 25; ++i) {
    const int n = base + i;
    loc[i] = (n < NN) ? cnt[n] : 0;
    sum += loc[i];
  }
  s[t] = sum;
  __syncthreads();
  for (int off = 1; off < 1024; off <<= 1) {
    const int v = (t >= off) ? s[t - off] : 0;
    __syncthreads();
    s[t] += v;
    __syncthreads();
  }
  int run = s[t] - sum;
#pragma unroll
  for (int i = 0; i < 25; ++i) {
    const int n = base + i;
    if (n < NN) {
      row_ptr[n] = run;
      next[n] = run;
      run += loc[i];
    }
  }
  if (t == 0) row_ptr[NN] = EE;
}

// ------- Scatter only: 64B AoS record {dst,src,attr-bf16} ----
// eattr read SEQUENTIAL; full-line record write (no read-for-ownership).
__global__ __launch_bounds__(256) void k_sp(
    const int* __restrict__ ei, int* __restrict__ next,
    char* __restrict__ rec, const float* __restrict__ eattr) {
  const int t = blockIdx.x * 256 + threadIdx.x;
  if (t < EE) {
    const int d = ei[EE + t];
    const int s = ei[t];
    const int slot = atomicAdd(&next[d], 1);
    const float* ep = &eattr[(size_t)t * DD];
    S8 a0, a1;
#pragma unroll
    for (int j = 0; j < 8; ++j) {
      a0.u[j] = f2bf_rne(ep[j]);
      a1.u[j] = f2bf_rne(ep[8 + j]);
    }
    char* rp = rec + (size_t)slot * RECB;
    int hdr[4] = {d, s, 0, 0};
    const f32x4 z4 = {0.f, 0.f, 0.f, 0.f};
    *(f32x4*)rp = *(const f32x4*)hdr;          // 16B: dst,src,pad
    *(short8*)(rp + 16) = a0.v;                // 16B attr lo
    *(short8*)(rp + 32) = a1.v;                // 16B attr hi
    *(f32x4*)(rp + 48) = z4;                   // pad -> full 64B line written
  }
}

// ---------------- K2: per-edge MLP via MFMA, dst-sorted -----------
// ONE 16-edge group per wave (25000 waves): narrow in-flight dst window keeps
// P1 reads + e_agg atomics L2-local. Register fast path for <=2 runs.
template <bool COORD>
__global__ __launch_bounds__(256, 4) void k_edge(
    const float* __restrict__ P1, const unsigned short* __restrict__ P2h,
    const float* __restrict__ pos, const char* __restrict__ rec,
    const unsigned short* __restrict__ wq, const float* __restrict__ mlp_w,
    const float* __restrict__ edge_b,
    const float* __restrict__ coord_w, const float* __restrict__ coord_b,
    float* __restrict__ e_agg, float* __restrict__ cu) {
  __shared__ __align__(16) float s_hs[4][16 * HS_STRIDE];
  __shared__ float s_diff[4][48];
  __shared__ float s_rad[4][16];
  __shared__ float s_red[4][16];
  const int tid = threadIdx.x, w = tid >> 6, lane = tid & 63;
  const int q = lane >> 4, m = lane & 15;

  const int g = blockIdx.x * 4 + w;                     // group id, 0..24999
  const int eb = g * 16;
  const char* rp = rec + (size_t)(eb + m) * RECB;
  const int dm = ((const int*)rp)[0];
  const int sm = ((const int*)rp)[1];

  S8 wB[2][4];
#pragma unroll
  for (int kc = 0; kc < 2; ++kc)
#pragma unroll
    for (int nc = 0; nc < 4; ++nc)
      wB[kc][nc].v = *(const short8*)(wq + WQ_EW + (kc * 4 + nc) * 512 + lane * 8);
  S8 w3B[4];
#pragma unroll
  for (int nc = 0; nc < 4; ++nc)
    w3B[nc].v = *(const short8*)(wq + WQ_W3 + nc * 512 + lane * 8);
  float w4r[4], cwr[4], ebr[4];
#pragma unroll
  for (int nc = 0; nc < 4; ++nc) {
    w4r[nc] = mlp_w[272 * 64 + nc * 16 + m];
    ebr[nc] = edge_b[nc * 16 + m];
    cwr[nc] = COORD ? coord_w[nc * 16 + m] : 0.f;
  }
  const float cb = COORD ? coord_b[0] : 0.f;

  const int pe = (lane < 48) ? (lane / 3) : 0;
  const int pc = lane - (lane / 3) * 3;

  f32x4 p1a[2], p1b[2];
  U8 p2r[2];
#pragma unroll
  for (int kc = 0; kc < 2; ++kc) {
    const float* pp1 = P1 + (size_t)dm * 64 + kc * 32 + q * 8;
    p1a[kc] = *(const f32x4*)pp1;
    p1b[kc] = *(const f32x4*)(pp1 + 4);
    p2r[kc].v = *(const u16x8*)(P2h + (size_t)sm * 64 + kc * 32 + q * 8);
  }
  if (lane < 48) {
    const int de = __shfl(dm, pe, 64), se = __shfl(sm, pe, 64);
    s_diff[w][lane] = pos[de * 3 + pc] - pos[se * 3 + pc];
  }
  S8 eaA;
#pragma unroll
  for (int j = 0; j < 8; ++j) eaA.u[j] = 0;
  if (lane < 32) {
    eaA.v = *(const short8*)(rp + 16 + q * 16);
  }
  if (lane < 16) {
    const float d0 = s_diff[w][lane * 3 + 0];
    const float d1 = s_diff[w][lane * 3 + 1];
    const float d2 = s_diff[w][lane * 3 + 2];
    s_rad[w][lane] = fmaf(d0, d0, fmaf(d1, d1, d2 * d2));
  }
  float radr[4];
#pragma unroll
  for (int r = 0; r < 4; ++r) radr[r] = s_rad[w][q * 4 + r];
  f32x4 c3[4];
#pragma unroll
  for (int nc = 0; nc < 4; ++nc) {
    f32x4 z = {0.f, 0.f, 0.f, 0.f};
    c3[nc] = __builtin_amdgcn_mfma_f32_16x16x32_bf16(eaA.v, w3B[nc].v, z, 0, 0, 0);
  }
#pragma unroll
  for (int nc = 0; nc < 4; ++nc)
#pragma unroll
    for (int r = 0; r < 4; ++r)
      s_hs[w][(q * 4 + r) * HS_STRIDE + nc * 16 + m] = fmaf(radr[r], w4r[nc], c3[nc][r]);
  S8 ahi[2], alo[2];
#pragma unroll
  for (int kc = 0; kc < 2; ++kc) {
    const float* hp = &s_hs[w][m * HS_STRIDE + kc * 32 + q * 8];
    f32x4 h0 = *(const f32x4*)hp;
    f32x4 h1 = *(const f32x4*)(hp + 4);
    h0 = h0 + p1a[kc];
    h1 = h1 + p1b[kc];
    float hv[8];
    *(f32x4*)&hv[0] = h0;
    *(f32x4*)&hv[4] = h1;
#pragma unroll
    for (int j = 0; j < 8; ++j) {
      const float h = silu_f(hv[j] + bfbits2f(p2r[kc].u[j]));
      const unsigned short hb = (unsigned short)(__float_as_uint(h) >> 16);
      ahi[kc].u[j] = hb;
      alo[kc].u[j] = f2bf_rne(h - bfbits2f(hb));
    }
  }
  f32x4 o[4];
#pragma unroll
  for (int nc = 0; nc < 4; ++nc) {
    f32x4 bi = {ebr[nc], ebr[nc], ebr[nc], ebr[nc]};
    o[nc] = bi;
  }
#pragma unroll
  for (int kc = 0; kc < 2; ++kc)
#pragma unroll
    for (int nc = 0; nc < 4; ++nc) {
      o[nc] = __builtin_amdgcn_mfma_f32_16x16x32_bf16(ahi[kc].v, wB[kc][nc].v, o[nc], 0, 0, 0);
      o[nc] = __builtin_amdgcn_mfma_f32_16x16x32_bf16(alo[kc].v, wB[kc][nc].v, o[nc], 0, 0, 0);
    }
#pragma unroll
  for (int nc = 0; nc < 4; ++nc)
#pragma unroll
    for (int r = 0; r < 4; ++r) o[nc][r] = silu_f(o[nc][r]);
  if (COORD) {
#pragma unroll
    for (int r = 0; r < 4; ++r) {
      float v = o[0][r] * cwr[0] + o[1][r] * cwr[1] + o[2][r] * cwr[2] + o[3][r] * cwr[3];
      v += __shfl_xor(v, 1, 64);
      v += __shfl_xor(v, 2, 64);
      v += __shfl_xor(v, 4, 64);
      v += __shfl_xor(v, 8, 64);
      if (m == 0) s_red[w][q * 4 + r] = v;
    }
  }

  // ---- e_agg reduction: run detection (dst sorted => monotone within group) ----
  const int d0  = __shfl(dm, 0, 64);
  const int d15 = __shfl(dm, 15, 64);
  const unsigned m1 = (unsigned)__ballot(lane < 16 && dm != d0) & 0xFFFFu;
  int b = 16;
  bool fast = true;
  if (m1 != 0) {
    b = __builtin_ctz(m1);
    const unsigned m2 = (unsigned)__ballot(lane < 16 && dm != d15) & 0xFFFFu;
    fast = (m2 == ((1u << b) - 1u));   // exactly two runs
  }
  if (fast) {
    float s0[4], s1[4];
#pragma unroll
    for (int nc = 0; nc < 4; ++nc) {
      s0[nc] = 0.f; s1[nc] = 0.f;
#pragma unroll
      for (int r = 0; r < 4; ++r) {
        const bool in0 = (q * 4 + r) < b;
        s0[nc] += in0 ? o[nc][r] : 0.f;
        s1[nc] += in0 ? 0.f : o[nc][r];
      }
    }
#pragma unroll
    for (int nc = 0; nc < 4; ++nc) {
      s0[nc] += __shfl_xor(s0[nc], 16, 64);
      s0[nc] += __shfl_xor(s0[nc], 32, 64);
    }
    const float v0 = (q == 0) ? s0[0] : (q == 1) ? s0[1] : (q == 2) ? s0[2] : s0[3];
    atomicAdd(&e_agg[(size_t)d0 * 64 + lane], v0);
    if (b < 16) {
#pragma unroll
      for (int nc = 0; nc < 4; ++nc) {
        s1[nc] += __shfl_xor(s1[nc], 16, 64);
        s1[nc] += __shfl_xor(s1[nc], 32, 64);
      }
      const float v1 = (q == 0) ? s1[0] : (q == 1) ? s1[1] : (q == 2) ? s1[2] : s1[3];
      atomicAdd(&e_agg[(size_t)d15 * 64 + lane], v1);
    }
  } else {
    // fallback: LDS transpose + serial run-compress (>=3 runs, rare)
#pragma unroll
    for (int nc = 0; nc < 4; ++nc)
#pragma unroll
      for (int r = 0; r < 4; ++r)
        s_hs[w][(q * 4 + r) * HS_STRIDE + nc * 16 + m] = o[nc][r];
    int cur_dst = -1;
    float accum = 0.f;
    for (int e = 0; e < 16; ++e) {
      const int dv = __shfl(dm, e, 64);
      const float v = s_hs[w][e * HS_STRIDE + lane];
      if (dv == cur_dst) {
        accum += v;
      } else {
        if (cur_dst >= 0) atomicAdd(&e_agg[(size_t)cur_dst * 64 + lane], accum);
        cur_dst = dv;
        accum = v;
      }
    }
    if (cur_dst >= 0) atomicAdd(&e_agg[(size_t)cur_dst * 64 + lane], accum);
  }

  if (COORD) {
    if (lane < 48) {
      const float s = silu_f(s_red[w][pe] + cb);
      atomicAdd(&cu[(size_t)__shfl(dm, pe, 64) * 3 + pc], s_diff[w][lane] * s);
    }
  }
}

// ------- K3: node MLP via MFMA (3-term split, near-fp32). COOPERATIVE:
// 4 waves share one 16-node tile (wave w owns h1 chunk nc=w, h2/P chunks w,w+4).
template <bool L0>
__global__ __launch_bounds__(256) void k_node(
    const float* __restrict__ x_in, float* __restrict__ e_agg,
    const unsigned short* __restrict__ wq,
    const float* __restrict__ nb1, const float* __restrict__ nb2,
    const float* __restrict__ pos_in, const float* __restrict__ cu,
    const int* __restrict__ row_ptr,
    float* __restrict__ x_out, float* __restrict__ pos_out,
    float* __restrict__ P1, unsigned short* __restrict__ P2h,
    const int* __restrict__ batch,
    float* __restrict__ g_sum, float* __restrict__ g_cnt) {
  __shared__ __align__(16) float sb[16 * 132];   // stride 132: 2-way banks (free)
  const int tid = threadIdx.x, w = tid >> 6, lane = tid & 63;
  const int q = lane >> 4, m = lane & 15;
  const int n0 = blockIdx.x * 16;
  const int nm = n0 + m;
  const bool vm = nm < NN;

  // ---- stage 1: A = [x | e_agg] (K=192), split hi/lo (all 4 waves; L1-shared)
  S8 axh[6], axl[6];
#pragma unroll
  for (int kc = 0; kc < 6; ++kc) {
    float hv[8] = {0.f, 0.f, 0.f, 0.f, 0.f, 0.f, 0.f, 0.f};
    if (vm) {
      const float* src = (kc < 4) ? (x_in + (size_t)nm * HIDC + kc * 32 + q * 8)
                                  : (e_agg + (size_t)nm * 64 + (kc - 4) * 32 + q * 8);
      *(f32x4*)&hv[0] = *(const f32x4*)src;
      *(f32x4*)&hv[4] = *(const f32x4*)(src + 4);
    }
    split8(hv, axh[kc], axl[kc]);
  }
  // ---- h1 chunk nc=w: silu(A @ nw1 + nb1) ----
  {
    const float b = nb1[w * 16 + m];
    f32x4 acc = {b, b, b, b};
#pragma unroll
    for (int kc = 0; kc < 6; ++kc) {
      S8 bh, bl;
      const unsigned short* fb = wq + WQ_NW1 + (w * 6 + kc) * 1024 + lane * 8;
      bh.v = *(const short8*)fb;
      bl.v = *(const short8*)(fb + 512);
      acc = mfma3(axh[kc], axl[kc], bh, bl, acc);
    }
#pragma unroll
    for (int r = 0; r < 4; ++r)
      sb[(q * 4 + r) * 132 + w * 16 + m] = silu_f(acc[r]);
  }
  __syncthreads();
  if (L0 && vm && w == 3) {   // pre-zero e_agg for layer 1 (after all waves read it)
    const f32x4 z = {0.f, 0.f, 0.f, 0.f};
    float* ez = e_agg + (size_t)nm * 64 + q * 8;
    *(f32x4*)ez = z; *(f32x4*)(ez + 4) = z;
    *(f32x4*)(ez + 32) = z; *(f32x4*)(ez + 36) = z;
  }
  // ---- read full h1 as A-fragments, split ----
  S8 ah[2], al[2];
#pragma unroll
  for (int kc = 0; kc < 2; ++kc) {
    float hv[8];
    const float* hp = &sb[m * 132 + kc * 32 + q * 8];
    *(f32x4*)&hv[0] = *(const f32x4*)hp;
    *(f32x4*)&hv[4] = *(const f32x4*)(hp + 4);
    split8(hv, ah[kc], al[kc]);
  }
  // ---- h2 chunks nc = w, w+4 ----
  f32x4 hh[2];
#pragma unroll
  for (int i = 0; i < 2; ++i) {
    const int nc = w + i * 4;
    const float b = nb2[nc * 16 + m];
    f32x4 acc = {b, b, b, b};
#pragma unroll
    for (int kc = 0; kc < 2; ++kc) {
      S8 bh, bl;
      const unsigned short* fb = wq + WQ_NW2 + (nc * 2 + kc) * 1024 + lane * 8;
      bh.v = *(const short8*)fb;
      bl.v = *(const short8*)(fb + 512);
      acc = mfma3(ah[kc], al[kc], bh, bl, acc);
    }
    hh[i] = acc;
  }
  if (L0) {
    __syncthreads();   // all h1 reads done before overwriting sb with x1
#pragma unroll
    for (int i = 0; i < 2; ++i) {
      const int nc = w + i * 4;
#pragma unroll
      for (int r = 0; r < 4; ++r) {
        const int n = n0 + q * 4 + r;
        sb[(q * 4 + r) * 132 + nc * 16 + m] = hh[i][r];
        if (n < NN) x_out[(size_t)n * HIDC + nc * 16 + m] = hh[i][r];
      }
    }
    if (w == 0 && lane < 48) {   // pos update (16 nodes x 3 comps)
      const int pe2 = lane / 3, pc2 = lane - pe2 * 3;
      const int n = n0 + pe2;
      if (n < NN) {
        const float dg = fmaxf((float)(row_ptr[n + 1] - row_ptr[n]), 1.f);
        pos_out[n * 3 + pc2] = pos_in[n * 3 + pc2] + cu[n * 3 + pc2] / dg;
      }
    }
    __syncthreads();
    // ---- P = x1 @ Wn (chunks nc=w -> P1 fp32, nc=w+4 -> P2 bf16) ----
    S8 a1h[4], a1l[4];
#pragma unroll
    for (int kc = 0; kc < 4; ++kc) {
      float hv[8];
      const float* hp = &sb[m * 132 + kc * 32 + q * 8];
      *(f32x4*)&hv[0] = *(const f32x4*)hp;
      *(f32x4*)&hv[4] = *(const f32x4*)(hp + 4);
      split8(hv, a1h[kc], a1l[kc]);
    }
#pragma unroll
    for (int i = 0; i < 2; ++i) {
      const int nc = w + i * 4;
      f32x4 acc = {0.f, 0.f, 0.f, 0.f};
#pragma unroll
      for (int kc = 0; kc < 4; ++kc) {
        S8 bh, bl;
        const unsigned short* fb = wq + WQ_WN + (nc * 4 + kc) * 1024 + lane * 8;
        bh.v = *(const short8*)fb;
        bl.v = *(const short8*)(fb + 512);
        acc = mfma3(a1h[kc], a1l[kc], bh, bl, acc);
      }
#pragma unroll
      for (int r = 0; r < 4; ++r) {
        const int n = n0 + q * 4 + r;
        if (n < NN) {
          if (i == 0) P1[(size_t)n * 64 + w * 16 + m] = acc[r];
          else        P2h[(size_t)n * 64 + w * 16 + m] = f2bf_rne(acc[r]);
        }
      }
    }
  } else {
    // ---- fused mean-pool partials (batch sorted; run-compress per lane) ----
    int curb = -1;
    float cnt2 = 0.f;
    float pacc[2];
#pragma unroll
    for (int r = 0; r < 4; ++r) {
      const int n = n0 + q * 4 + r;
      if (n < NN) {
        const int bg = batch[n];
        if (bg != curb) {
          if (curb >= 0) {
#pragma unroll
            for (int i = 0; i < 2; ++i)
              atomicAdd(&g_sum[curb * HIDC + (w + i * 4) * 16 + m], pacc[i]);
            if (w == 0 && m == 0) atomicAdd(&g_cnt[curb], cnt2);
          }
          curb = bg;
          pacc[0] = hh[0][r];
          pacc[1] = hh[1][r];
          cnt2 = 1.f;
        } else {
          pacc[0] += hh[0][r];
          pacc[1] += hh[1][r];
          cnt2 += 1.f;
        }
      }
    }
    if (curb >= 0) {
#pragma unroll
      for (int i = 0; i < 2; ++i)
        atomicAdd(&g_sum[curb * HIDC + (w + i * 4) * 16 + m], pacc[i]);
      if (w == 0 && m == 0) atomicAdd(&g_cnt[curb], cnt2);
    }
  }
}

// ---------------- K5: relu(mean) -> relu(@w1+b1) -> @w2+b2 ----------------
__global__ __launch_bounds__(128) void k_final(
    const float* __restrict__ g_sum, const float* __restrict__ g_cnt,
    const float* __restrict__ w1, const float* __restrict__ b1,
    const float* __restrict__ w2, const float* __restrict__ b2,
    float* __restrict__ out) {
  __shared__ float sg[128];
  __shared__ float sh[128];
  const int g = blockIdx.x, j = threadIdx.x;
  const float c = fmaxf(g_cnt[g], 1.f);
  sg[j] = fmaxf(g_sum[g * HIDC + j] / c, 0.f);
  __syncthreads();
  float a = b1[j];
  for (int k = 0; k < 128; ++k) a += sg[k] * w1[k * 128 + j];
  sh[j] = fmaxf(a, 0.f);
  __syncthreads();
  if (j < OUTC) {
    float o = b2[j];
    for (int k = 0; k < 128; ++k) o += sh[k] * w2[k * OUTC + j];
    out[g * OUTC + j] = o;
  }
}

extern "C" void kernel_launch(void* const* d_in, const int* in_sizes, int n_in,
                              void* d_out, int out_size, void* d_ws, size_t ws_size,
                              hipStream_t stream) {
  const float* x     = (const float*)d_in[0];
  const float* pos   = (const float*)d_in[1];
  const float* eattr = (const float*)d_in[2];
  const int*   ei    = (const int*)d_in[3];
  const int*   batch = (const int*)d_in[4];
  const float* mlp_w[2]   = {(const float*)d_in[5],  (const float*)d_in[14]};
  const float* edge_w[2]  = {(const float*)d_in[6],  (const float*)d_in[15]};
  const float* edge_b[2]  = {(const float*)d_in[7],  (const float*)d_in[16]};
  const float* coord_w[2] = {(const float*)d_in[8],  (const float*)d_in[17]};
  const float* coord_b[2] = {(const float*)d_in[9],  (const float*)d_in[18]};
  const float* nw1[2]     = {(const float*)d_in[10], (const float*)d_in[19]};
  const float* nb1[2]     = {(const float*)d_in[11], (const float*)d_in[20]};
  const float* nw2[2]     = {(const float*)d_in[12], (const float*)d_in[21]};
  const float* nb2[2]     = {(const float*)d_in[13], (const float*)d_in[22]};
  const float* ow1 = (const float*)d_in[23];
  const float* ob1 = (const float*)d_in[24];
  const float* ow2 = (const float*)d_in[25];
  const float* ob2 = (const float*)d_in[26];
  float* out = (float*)d_out;

  char* p = (char*)d_ws;
  auto alloc = [&](size_t bytes) {
    void* r = (void*)p;
    p += (bytes + 255) & ~(size_t)255;
    return r;
  };
  float* P1            = (float*)alloc((size_t)NN * 64 * 4);
  unsigned short* P2h  = (unsigned short*)alloc((size_t)NN * 64 * 2);
  // ---- cnt: zeroed by small memset (must be 0 BEFORE k_hist's histogram) ----
  int* cnt             = (int*)alloc((size_t)NN * 4);
  // ---- zero-region handled by k_hist's fused zero blocks ----
  char* zero_base      = p;
  float* e_agg         = (float*)alloc((size_t)NN * 64 * 4);
  float* cu            = (float*)alloc((size_t)NN * 3 * 4);
  float* g_sum         = (float*)alloc((size_t)GG * HIDC * 4);
  float* g_cnt         = (float*)alloc((size_t)GG * 4);
  const size_t zero_sz = (size_t)(p - zero_base);
  // ---- non-zeroed scratch ----
  int* row_ptr         = (int*)alloc((size_t)(NN + 1) * 4);
  int* nxt             = (int*)alloc((size_t)NN * 4);
  char* rec            = (char*)alloc((size_t)EE * RECB);
  float* x1            = (float*)alloc((size_t)NN * HIDC * 4);
  float* pos1          = (float*)alloc((size_t)NN * 3 * 4);
  unsigned short* wqb  = (unsigned short*)alloc((size_t)2 * WQ_LAYER * 2);

  (void)hipMemsetAsync(cnt, 0, (size_t)NN * 4, stream);

  // ---- dispatch 1: P-precompute + histogram + weight prep + zero-fill ----
  k_hist<<<NODEBLK + SCATBLK + 2 + ZBLK, 256, 0, stream>>>(ei, cnt,
      nw1[0], nw2[0], mlp_w[0], edge_w[0],
      nw1[1], nw2[1], mlp_w[1], edge_w[1], wqb,
      (f32x4*)zero_base, (int)(zero_sz / 16),
      x, P1, P2h);
  k_scan<<<1, 1024, 0, stream>>>(cnt, row_ptr, nxt);
  k_sp<<<SCATBLK, 256, 0, stream>>>(ei, nxt, rec, eattr);

  // ---- layer 0 ----
  k_edge<true><<<EDGEBLK, 256, 0, stream>>>(P1, P2h, pos, rec,
      wqb, mlp_w[0], edge_b[0], coord_w[0], coord_b[0], e_agg, cu);
  k_node<true><<<NTILES, 256, 0, stream>>>(x, e_agg, wqb, nb1[0], nb2[0],
      pos, cu, row_ptr, x1, pos1, P1, P2h, batch, g_sum, g_cnt);

  // ---- layer 1 ----
  k_edge<false><<<EDGEBLK, 256, 0, stream>>>(P1, P2h, pos1, rec,
      wqb + WQ_LAYER, mlp_w[1], edge_b[1], coord_w[1], coord_b[1], e_agg, cu);
  k_node<false><<<NTILES, 256, 0, stream>>>(x1, e_agg, wqb + WQ_LAYER,
      nb1[1], nb2[1], pos1, cu, row_ptr, x1, pos1, P1, P2h,
      batch, g_sum, g_cnt);

  // ---- head ----
  k_final<<<GG, 128, 0, stream>>>(g_sum, g_cnt, ow1, ob1, ow2, ob2, out);
}